// Round 8
// baseline (468.416 us; speedup 1.0000x reference)
//
#include <hip/hip_runtime.h>

// PureLSTM: B=4096, T=512, I=32, H=16. One wave64 per batch element.
// R6 = R5 with the serial chain de-LDS'd:
//  - xor16 gate exchange: v_permlane16_swap_b32 (VALU) + xor recovery
//  - xor1 h-pair exchange: DPP quad_perm [1,0,3,2]
//  - log2e folded into weights/biases (2*log2e for g rows) -> raw v_exp_f32
//  - fdot2 depth 2 (4 accumulators), xg read prefetched 2 steps ahead
// Chain keeps exactly one DS op (prefetched xg ds_read_b32).

constexpr int BATCH = 4096;
constexpr int SEQ   = 512;
constexpr int ISZ   = 32;
constexpr int HSZ   = 16;
constexpr int CH    = 32;        // timesteps per chunk
constexpr int NCH   = SEQ / CH;  // 16 chunks
constexpr int XGS   = 66;        // xg LDS row stride (floats)

constexpr float L2E = 1.44269504088896340736f;

typedef __fp16 h2  __attribute__((ext_vector_type(2)));
typedef __fp16 v8h __attribute__((ext_vector_type(8)));
typedef float  v4f __attribute__((ext_vector_type(4)));

union H8 { v8h v; h2 h[4]; };

__device__ __forceinline__ float rcpf_(float x) { return __builtin_amdgcn_rcpf(x); }
__device__ __forceinline__ float exp2f_(float x) { return __builtin_amdgcn_exp2f(x); }
__device__ __forceinline__ float rl_f(float v, int l) {
  return __int_as_float(__builtin_amdgcn_readlane(__float_as_int(v), l));
}
// lane^1 via DPP quad_perm [1,0,3,2] (ctrl 0xB1)
__device__ __forceinline__ float dpp_xor1(float v) {
  return __int_as_float(__builtin_amdgcn_update_dpp(
      __float_as_int(v), __float_as_int(v), 0xB1, 0xF, 0xF, true));
}

__global__ __launch_bounds__(256, 4) void lstm_fused(
    const float* __restrict__ x, const float* __restrict__ Wih,
    const float* __restrict__ Whh, const float* __restrict__ bih,
    const float* __restrict__ bhh, const float* __restrict__ fcw,
    const float* __restrict__ fcb, float* __restrict__ out) {
  const int lane = threadIdx.x & 63;
  const int wid  = __builtin_amdgcn_readfirstlane(threadIdx.x >> 6);
  const int bidx = blockIdx.x * 4 + wid;
  const int col  = lane & 15;   // MFMA col / within-gate index
  const int kg   = lane >> 4;   // MFMA k-group / gate quarter
  const bool q1  = (kg == 1);   // f-lanes
  const bool q3  = (kg == 3);   // o-lanes
  const bool isg = (kg == 2);   // g-lanes: tanh pre-activation
  const float sA = isg ?  2.f :  1.f;
  const float sB = isg ? -1.f :  0.f;
  const float M2 = -2.f * L2E;  // for tanh(c) = 2*sig(2c)-1 in exp2 domain

  __shared__ float xg_s[4][CH * XGS];  // per-wave private xg (33792 B/block)

  // ---- B-fragments: Wih as f16 (log2e-prescaled), B[k][n], n=col, k=kg*8+e
  H8 bfr[4];
  float bb[4];
#pragma unroll
  for (int nt = 0; nt < 4; ++nt) {
    const int g = nt * 16 + col;
    const float sc = (nt == 2) ? 2.f * L2E : L2E;  // g-gate rows get 2*log2e
    const float* wp = Wih + g * ISZ + kg * 8;
    const v4f w0 = *reinterpret_cast<const v4f*>(wp);
    const v4f w1 = *reinterpret_cast<const v4f*>(wp + 4);
    bfr[nt].h[0] = __builtin_amdgcn_cvt_pkrtz(w0.x * sc, w0.y * sc);
    bfr[nt].h[1] = __builtin_amdgcn_cvt_pkrtz(w0.z * sc, w0.w * sc);
    bfr[nt].h[2] = __builtin_amdgcn_cvt_pkrtz(w1.x * sc, w1.y * sc);
    bfr[nt].h[3] = __builtin_amdgcn_cvt_pkrtz(w1.z * sc, w1.w * sc);
    bb[nt] = (bih[g] + bhh[g]) * sc;  // bias folded into MFMA C, prescaled
  }

  // ---- Whh row for own gate (row = lane), f16 pairs, log2e-prescaled ----
  int whh[8];
  {
    const float wsc = isg ? 2.f * L2E : L2E;
    const float* wp = Whh + lane * HSZ;
#pragma unroll
    for (int j = 0; j < 4; ++j) {
      const v4f v = *reinterpret_cast<const v4f*>(wp + 4 * j);
      whh[2 * j]     = __builtin_bit_cast(int, __builtin_amdgcn_cvt_pkrtz(v.x * wsc, v.y * wsc));
      whh[2 * j + 1] = __builtin_bit_cast(int, __builtin_amdgcn_cvt_pkrtz(v.z * wsc, v.w * wsc));
    }
  }

  const float* xb_ = x + (size_t)bidx * (SEQ * ISZ);
  const int aoff0 = col * ISZ + kg * 8;         // A tile mt=0 (t rows 0..15)
  const int aoff1 = (16 + col) * ISZ + kg * 8;  // A tile mt=1

  // prefetch chunk 0 x into registers (per-lane dense, 4KB/wave/chunk)
  v4f pf[4];
  pf[0] = *reinterpret_cast<const v4f*>(xb_ + aoff0);
  pf[1] = *reinterpret_cast<const v4f*>(xb_ + aoff0 + 4);
  pf[2] = *reinterpret_cast<const v4f*>(xb_ + aoff1);
  pf[3] = *reinterpret_cast<const v4f*>(xb_ + aoff1 + 4);

  // xg LDS pointers
  float* wbase = &xg_s[wid][(kg * 4) * XGS + col];  // MFMA D write base
  const float* xrd = &xg_s[wid][lane];              // serial read base (g=lane)

  int hs_pk[8];  // packed f16 h pairs (uniform via readlane)
#pragma unroll
  for (int j = 0; j < 8; ++j) hs_pk[j] = 0;
  float c = 0.f, hlast = 0.f;

  for (int ch = 0; ch < NCH; ++ch) {
    // convert current x regs -> A fragments
    H8 afr0, afr1;
    afr0.h[0] = __builtin_amdgcn_cvt_pkrtz(pf[0].x, pf[0].y);
    afr0.h[1] = __builtin_amdgcn_cvt_pkrtz(pf[0].z, pf[0].w);
    afr0.h[2] = __builtin_amdgcn_cvt_pkrtz(pf[1].x, pf[1].y);
    afr0.h[3] = __builtin_amdgcn_cvt_pkrtz(pf[1].z, pf[1].w);
    afr1.h[0] = __builtin_amdgcn_cvt_pkrtz(pf[2].x, pf[2].y);
    afr1.h[1] = __builtin_amdgcn_cvt_pkrtz(pf[2].z, pf[2].w);
    afr1.h[2] = __builtin_amdgcn_cvt_pkrtz(pf[3].x, pf[3].y);
    afr1.h[3] = __builtin_amdgcn_cvt_pkrtz(pf[3].z, pf[3].w);

    // issue next-chunk x loads (prefetch distance = 1 chunk = 32 steps)
    {
      const int nc = (ch + 1 < NCH) ? (ch + 1) : 0;
      const float* nx = xb_ + (size_t)nc * (CH * ISZ);
      pf[0] = *reinterpret_cast<const v4f*>(nx + aoff0);
      pf[1] = *reinterpret_cast<const v4f*>(nx + aoff0 + 4);
      pf[2] = *reinterpret_cast<const v4f*>(nx + aoff1);
      pf[3] = *reinterpret_cast<const v4f*>(nx + aoff1 + 4);
    }
    __builtin_amdgcn_sched_barrier(0);  // pin prefetch issue here

    // xg = x . Wih^T + bias (all log2e-prescaled): 8 MFMAs, D -> LDS
#pragma unroll
    for (int nt = 0; nt < 4; ++nt) {
      const v4f ci = {bb[nt], bb[nt], bb[nt], bb[nt]};
      const v4f d0 = __builtin_amdgcn_mfma_f32_16x16x32_f16(afr0.v, bfr[nt].v, ci, 0, 0, 0);
      const v4f d1 = __builtin_amdgcn_mfma_f32_16x16x32_f16(afr1.v, bfr[nt].v, ci, 0, 0, 0);
#pragma unroll
      for (int r = 0; r < 4; ++r) {
        wbase[r * XGS + nt * 16]        = d0[r];  // t = kg*4+r
        wbase[(16 + r) * XGS + nt * 16] = d1[r];  // t = 16+kg*4+r
      }
    }

    // ---- serial 32 steps; xg read 2 ahead (re-primed per chunk) ----
    float xA = xrd[0];
    float xB = xrd[XGS];
#pragma unroll
    for (int s = 0; s < CH; ++s) {
      const float xC = xrd[(s + 2 < CH) ? (s + 2) * XGS : 0];
      // h-dot: 8 x v_dot2_f32_f16, 4 accumulators depth 2
      float t0 = __builtin_amdgcn_fdot2(__builtin_bit_cast(h2, whh[0]),
                                        __builtin_bit_cast(h2, hs_pk[0]), xA, false);
      float t1 = __builtin_amdgcn_fdot2(__builtin_bit_cast(h2, whh[2]),
                                        __builtin_bit_cast(h2, hs_pk[2]), 0.f, false);
      float t2 = __builtin_amdgcn_fdot2(__builtin_bit_cast(h2, whh[4]),
                                        __builtin_bit_cast(h2, hs_pk[4]), 0.f, false);
      float t3 = __builtin_amdgcn_fdot2(__builtin_bit_cast(h2, whh[6]),
                                        __builtin_bit_cast(h2, hs_pk[6]), 0.f, false);
      t0 = __builtin_amdgcn_fdot2(__builtin_bit_cast(h2, whh[1]),
                                  __builtin_bit_cast(h2, hs_pk[1]), t0, false);
      t1 = __builtin_amdgcn_fdot2(__builtin_bit_cast(h2, whh[3]),
                                  __builtin_bit_cast(h2, hs_pk[3]), t1, false);
      t2 = __builtin_amdgcn_fdot2(__builtin_bit_cast(h2, whh[5]),
                                  __builtin_bit_cast(h2, hs_pk[5]), t2, false);
      t3 = __builtin_amdgcn_fdot2(__builtin_bit_cast(h2, whh[7]),
                                  __builtin_bit_cast(h2, hs_pk[7]), t3, false);
      const float pre = (t0 + t1) + (t2 + t3);  // already in exp2 domain
      // own-gate activation: sigma = rcp(1+2^-pre); tanh lanes: 2*sig-1
      const float e_ = exp2f_(-pre);
      const float y  = fmaf(sA, rcpf_(1.f + e_), sB);
      // partner at lane^32: permlane32_swap + xor recovery (HW-verified)
      int va = __float_as_int(y), vb = va;
      asm volatile("s_nop 0\n\tv_permlane32_swap_b32 %0, %1\n\ts_nop 0"
                   : "+v"(va), "+v"(vb));
      const float prt = __int_as_float(va ^ vb ^ __float_as_int(y));
      // i/g lanes both compute i*g; ship to f/o lanes via permlane16_swap
      const float p1 = y * prt;
      int wa = __float_as_int(p1), wb = wa;
      asm volatile("s_nop 0\n\tv_permlane16_swap_b32 %0, %1\n\ts_nop 0"
                   : "+v"(wa), "+v"(wb));
      const float p1x = __int_as_float(wa ^ wb ^ __float_as_int(p1));
      const float sf  = q3 ? prt : y;   // sigma_f on f(own) and o(partner)
      c = fmaf(sf, c, p1x);             // valid (duplicated) on f and o lanes
      const float e2 = exp2f_(c * M2);
      const float th = fmaf(2.f, rcpf_(1.f + e2), -1.f);
      const float so = q1 ? prt : y;    // sigma_o on f(partner) and o(own)
      hlast = so * th;                  // h_k on lanes 16+k (and 48+k)
      // pack h pairs -> f16 via DPP lane^1, broadcast 8 words
      const float hx = dpp_xor1(hlast);
      const int hpi = __builtin_bit_cast(int, __builtin_amdgcn_cvt_pkrtz(hlast, hx));
#pragma unroll
      for (int j = 0; j < 8; ++j)
        hs_pk[j] = __builtin_amdgcn_readlane(hpi, 16 + 2 * j);
      xA = xB; xB = xC;
    }
  }

  // ---- epilogue: out[b] = sigmoid(h . fc_w + fc_b), h fp32 from f-lanes ----
  float s = fcb[0];
#pragma unroll
  for (int k = 0; k < HSZ; ++k) s = fmaf(rl_f(hlast, 16 + k), fcw[k], s);
  if (lane == 0) out[bidx] = rcpf_(1.f + exp2f_(-s * L2E));
}

extern "C" void kernel_launch(void* const* d_in, const int* in_sizes, int n_in,
                              void* d_out, int out_size, void* d_ws, size_t ws_size,
                              hipStream_t stream) {
  const float* x   = (const float*)d_in[0];
  const float* Wih = (const float*)d_in[1];
  const float* Whh = (const float*)d_in[2];
  const float* bih = (const float*)d_in[3];
  const float* bhh = (const float*)d_in[4];
  const float* fcw = (const float*)d_in[5];
  const float* fcb = (const float*)d_in[6];
  float* out = (float*)d_out;

  dim3 grid(BATCH / 4);
  dim3 block(256);
  hipLaunchKernelGGL(lstm_fused, grid, block, 0, stream,
                     x, Wih, Whh, bih, bhh, fcw, fcb, out);
}